// Round 2
// baseline (897.497 us; speedup 1.0000x reference)
//
#include <hip/hip_runtime.h>

// NearestMean: out = labels[searchsorted(thresholds, X, side='right')]
// X: fp32, 142,848,000 elems (571.4 MB). out: int32 (571.4 MB).
// Pure zero-reuse streaming: roofline ~181 us @ 6.3 TB/s achievable.
//
// This version:
//  - capped-grid grid-stride: 2048 blocks x 256 thr = 8 blocks/CU x 256 CU
//    (full 32-wave/CU occupancy, ~68 float4 iters/thread).
//  - nontemporal load/store on both streams via clang ext_vector types
//    (__builtin_nontemporal_* rejects HIP_vector_type classes).
//  - branchless 3-cmp select chain (VALU is far from the bottleneck).

typedef float  fx4 __attribute__((ext_vector_type(4)));
typedef int    ix4 __attribute__((ext_vector_type(4)));

__global__ __launch_bounds__(256) void NearestMean_kernel(
    const fx4* __restrict__ x4,
    const float* __restrict__ thr,
    const int* __restrict__ labs,
    ix4* __restrict__ out4,
    const float* __restrict__ x_tail,   // scalar view for tail
    int* __restrict__ out_tail,
    long long n4, long long n_tail)     // n_tail = n - 4*n4 (0..3)
{
    const float t0 = thr[0], t1 = thr[1], t2 = thr[2];
    const int   l0 = labs[0], l1 = labs[1], l2 = labs[2], l3 = labs[3];

    const long long stride = (long long)gridDim.x * blockDim.x;
    for (long long i = (long long)blockIdx.x * blockDim.x + threadIdx.x;
         i < n4; i += stride) {
        fx4 v = __builtin_nontemporal_load(&x4[i]);
        ix4 o;
        o.x = v.x >= t2 ? l3 : (v.x >= t1 ? l2 : (v.x >= t0 ? l1 : l0));
        o.y = v.y >= t2 ? l3 : (v.y >= t1 ? l2 : (v.y >= t0 ? l1 : l0));
        o.z = v.z >= t2 ? l3 : (v.z >= t1 ? l2 : (v.z >= t0 ? l1 : l0));
        o.w = v.w >= t2 ? l3 : (v.w >= t1 ? l2 : (v.w >= t0 ? l1 : l0));
        __builtin_nontemporal_store(o, &out4[i]);
    }

    // Tail (n not divisible by 4 — not the case here, but be safe).
    if (blockIdx.x == 0 && (long long)threadIdx.x < n_tail) {
        long long j = 4 * n4 + (long long)threadIdx.x;
        float v = x_tail[j];
        out_tail[j] = v >= t2 ? l3 : (v >= t1 ? l2 : (v >= t0 ? l1 : l0));
    }
}

extern "C" void kernel_launch(void* const* d_in, const int* in_sizes, int n_in,
                              void* d_out, int out_size, void* d_ws, size_t ws_size,
                              hipStream_t stream) {
    const float* X    = (const float*)d_in[0];
    const float* thr  = (const float*)d_in[1];
    const int*   labs = (const int*)d_in[2];
    int* out = (int*)d_out;

    long long n = (long long)in_sizes[0];
    long long n4 = n / 4;
    long long n_tail = n - 4 * n4;

    const int block = 256;
    long long grid = (n4 + block - 1) / block;
    if (grid > 2048) grid = 2048;   // 8 blocks/CU x 256 CU — full occupancy
    if (grid < 1)    grid = 1;

    NearestMean_kernel<<<(dim3)(unsigned)grid, block, 0, stream>>>(
        (const fx4*)X, thr, labs, (ix4*)out, X, out, n4, n_tail);
}